// Round 6
// baseline (168.736 us; speedup 1.0000x reference)
//
#include <hip/hip_runtime.h>
#include <stdint.h>

#define S_LEN 2048
#define EMBED 1024
#define HEADS 16
#define HD 64
#define M_ROWS 4096      // B*S
#define N_QKV 3072
#define KDIM 1024
#define SP 2336          // padded vT row length: 128 + 2048 + 160
#define CLP2 200         // qkv C-tile LDS col stride (u16)

typedef __attribute__((ext_vector_type(8))) short short8;
typedef __attribute__((ext_vector_type(4))) float f32x4;

__device__ __forceinline__ unsigned short f2bf(float f) {
  union { float f; uint32_t u; } c; c.f = f;
  uint32_t u = c.u;
  u += 0x7fffu + ((u >> 16) & 1u);  // round-to-nearest-even
  return (unsigned short)(u >> 16);
}

// async global->LDS, 16B per lane; lds base must be wave-uniform (HW adds lane*16)
__device__ __forceinline__ void gload_lds16(const unsigned short* g, unsigned short* l) {
  __builtin_amdgcn_global_load_lds(
      (const __attribute__((address_space(1))) void*)g,
      (__attribute__((address_space(3))) void*)l, 16, 0, 0);
}

// ---------------- fused fp32->bf16 convert (x, Wqkv, Wo) + vT halo zero ----------------
#define XQ 1048576
#define WQKVQ 786432
#define WOQ 262144
#define CVTQ (XQ + WQKVQ + WOQ)      // 2,097,152 quads
__global__ __launch_bounds__(256) void cvt3_kernel(
    const float* __restrict__ x, const float* __restrict__ wqkv, const float* __restrict__ wo,
    unsigned short* __restrict__ xb, unsigned short* __restrict__ wqkvb, unsigned short* __restrict__ wob,
    unsigned short* __restrict__ vTp) {
  int i = blockIdx.x * blockDim.x + threadIdx.x;
  if (i < CVTQ) {
    const float* s; unsigned short* d; int off;
    if (i < XQ)               { s = x;    d = xb;    off = i; }
    else if (i < XQ + WQKVQ)  { s = wqkv; d = wqkvb; off = i - XQ; }
    else                      { s = wo;   d = wob;   off = i - XQ - WQKVQ; }
    float4 f = reinterpret_cast<const float4*>(s)[off];
    ushort4 o;
    o.x = f2bf(f.x); o.y = f2bf(f.y); o.z = f2bf(f.z); o.w = f2bf(f.w);
    reinterpret_cast<ushort4*>(d)[off] = o;
  } else {
    int j = i - CVTQ;                      // 0..147455
    int row = j / 72, p = j % 72;          // row = bh*64+d
    int off = row * 584 + (p < 32 ? p : 544 + (p - 32));  // left 128 u16 / right 160 u16
    reinterpret_cast<ushort4*>(vTp)[off] = (ushort4){0, 0, 0, 0};
  }
}

// ---------------- QKV GEMM: 256x192 tile, 32 phases of BK=32, 5-slab ring ----------------
// Depth-3 counted prefetch: stage slab h+3 while computing slab h.
// Wave-role staging split: waves 0-3 stage A (4 x 1KB units), waves 4-7 stage B (3 units)
// -> per-wave vmcnt constant: 12 | 9 steady state; NO vmcnt(0) until the tail.
// ONE barrier per phase (32 total): ring distance 3 < ring size 5 => >=2 barriers between
// a slab's last reader and its next writer.
#define QKV_PHASE(DO_STAGE, NA, NB)                                            \
  {                                                                            \
    if (DO_STAGE) {                                                            \
      if (wave < 4) {                                                          \
        gload_lds16(g0 + k0, smem + sow + ldsu);                               \
        gload_lds16(g1 + k0, smem + sow + ldsu + 512);                         \
        gload_lds16(g2 + k0, smem + sow + ldsu + 1024);                        \
        gload_lds16(g3 + k0, smem + sow + ldsu + 1536);                        \
      } else {                                                                 \
        gload_lds16(g0 + k0, smem + sow + ldsu);                               \
        gload_lds16(g1 + k0, smem + sow + ldsu + 512);                         \
        gload_lds16(g2 + k0, smem + sow + ldsu + 1024);                        \
      }                                                                        \
    }                                                                          \
    __builtin_amdgcn_sched_barrier(0);                                         \
    if (wave < 4) asm volatile("s_waitcnt vmcnt(" #NA ")" ::: "memory");       \
    else          asm volatile("s_waitcnt vmcnt(" #NB ")" ::: "memory");       \
    __builtin_amdgcn_sched_barrier(0);                                         \
    __builtin_amdgcn_s_barrier();                                              \
    __builtin_amdgcn_sched_barrier(0);                                         \
    short8 af[4], bf[6];                                                       \
    _Pragma("unroll")                                                          \
    for (int mt = 0; mt < 4; mt++)                                             \
      af[mt] = *reinterpret_cast<const short8*>(&smem[so + abase + mt * 512]); \
    _Pragma("unroll")                                                          \
    for (int nt = 0; nt < 6; nt++)                                             \
      bf[nt] = *reinterpret_cast<const short8*>(&smem[so + bbase + nt * 512]); \
    asm volatile("s_waitcnt lgkmcnt(0)" ::: "memory");                         \
    __builtin_amdgcn_sched_barrier(0);                                         \
    __builtin_amdgcn_s_setprio(1);                                             \
    _Pragma("unroll")                                                          \
    for (int mt = 0; mt < 4; mt++)                                             \
      _Pragma("unroll")                                                        \
      for (int nt = 0; nt < 6; nt++)                                           \
        acc[mt][nt] = __builtin_amdgcn_mfma_f32_16x16x32_bf16(                 \
            af[mt], bf[nt], acc[mt][nt], 0, 0, 0);                             \
    __builtin_amdgcn_s_setprio(0);                                             \
    __builtin_amdgcn_sched_barrier(0);                                         \
  }

__global__ __launch_bounds__(512, 2) void gemm_qkv(
    const unsigned short* __restrict__ A, const unsigned short* __restrict__ Bm,
    const float* __restrict__ bias, const int* __restrict__ pm,
    unsigned short* __restrict__ qo, unsigned short* __restrict__ ko,
    unsigned short* __restrict__ vTp)
{
  // 5 slabs x (A 256x32 + B 192x32) u16 = 5 x 14336 u16 = 143,360 B
  // epilogue C [256][200] u16 = 51,200 u16 aliased over slabs 0-3
  __shared__ __align__(16) unsigned short smem[71680];
  const int t = threadIdx.x, wave = t >> 6, lane = t & 63;
  const int m16 = lane & 15, q4 = lane >> 4;
  const int wm = wave >> 1, wn = wave & 1;          // 4x2 waves, each 64 rows x 96 cols
  const int bid = blockIdx.x;
  const int mb = bid >> 4, nb = bid & 15;           // bid%8 == nb%8 -> XCD affinity

  // ---- staging sources: unit = 16 rows x 32k = 1KB; lane -> (row, kseg) pre-swizzled ----
  const int srow16 = lane >> 2;                         // row within unit
  const int kseg = (lane & 3) ^ ((lane >> 3) & 3);      // inverse of read-side swizzle
  const unsigned short *g0, *g1, *g2, *g3;
  int ldsu;                                             // wave-uniform LDS unit base (u16)
  if (wave < 4) {                                       // A: 16 units, 4 per wave
    int u0 = wave * 4;
    g0 = A + (size_t)(mb * 256 + (u0 + 0) * 16 + srow16) * KDIM + kseg * 8;
    g1 = A + (size_t)(mb * 256 + (u0 + 1) * 16 + srow16) * KDIM + kseg * 8;
    g2 = A + (size_t)(mb * 256 + (u0 + 2) * 16 + srow16) * KDIM + kseg * 8;
    g3 = A + (size_t)(mb * 256 + (u0 + 3) * 16 + srow16) * KDIM + kseg * 8;
    ldsu = u0 * 512;
  } else {                                              // B: 12 units, 3 per wave
    int u0 = (wave - 4) * 3;
    g0 = Bm + (size_t)(nb * 192 + (u0 + 0) * 16 + srow16) * KDIM + kseg * 8;
    g1 = Bm + (size_t)(nb * 192 + (u0 + 1) * 16 + srow16) * KDIM + kseg * 8;
    g2 = Bm + (size_t)(nb * 192 + (u0 + 2) * 16 + srow16) * KDIM + kseg * 8;
    g3 = g2;                                            // unused
    ldsu = 8192 + u0 * 512;
  }

  // ---- fragment read addressing (u16 offsets within a slab) ----
  const int sa = q4 ^ ((m16 >> 1) & 3);                 // swizzled seg
  const int abase = (wm * 64 + m16) * 32 + sa * 8;      // + mt*512
  const int bbase = 8192 + (wn * 96 + m16) * 32 + sa * 8;  // + nt*512

  f32x4 acc[4][6];
#pragma unroll
  for (int i_ = 0; i_ < 4; i_++)
#pragma unroll
    for (int j_ = 0; j_ < 6; j_++) acc[i_][j_] = (f32x4){0.f, 0.f, 0.f, 0.f};

  // ---- prologue: stage slabs 0,1,2 (depth 3) ----
  int so = 0, sow = 0, k0 = 0;
#pragma unroll
  for (int s = 0; s < 3; ++s) {
    if (wave < 4) {
      gload_lds16(g0 + k0, smem + sow + ldsu);
      gload_lds16(g1 + k0, smem + sow + ldsu + 512);
      gload_lds16(g2 + k0, smem + sow + ldsu + 1024);
      gload_lds16(g3 + k0, smem + sow + ldsu + 1536);
    } else {
      gload_lds16(g0 + k0, smem + sow + ldsu);
      gload_lds16(g1 + k0, smem + sow + ldsu + 512);
      gload_lds16(g2 + k0, smem + sow + ldsu + 1024);
    }
    sow += 14336; k0 += 32;
  }
  __builtin_amdgcn_sched_barrier(0);
  // now: sow = 3*14336 (slab 3's home), k0 = 96 (slab 3's k-offset)

  // ---- main loop: phases 0..28 stage slab h+3; tail 29..31 drain ----
  for (int h = 0; h < 29; ++h) {
    QKV_PHASE(true, 12, 9);
    so += 14336;  if (so  == 71680) so  = 0;
    sow += 14336; if (sow == 71680) sow = 0;
    k0 += 32;
  }
  QKV_PHASE(false, 8, 6);
  so += 14336; if (so == 71680) so = 0;
  QKV_PHASE(false, 4, 3);
  so += 14336; if (so == 71680) so = 0;
  QKV_PHASE(false, 0, 0);
  __syncthreads();   // all frag reads done before smem reuse as Cld

  // ---- epilogue: C via LDS [256][CLP2], then q/k/vT writeout ----
  float pmv[4][4];
#pragma unroll
  for (int mt = 0; mt < 4; mt++)
#pragma unroll
    for (int reg = 0; reg < 4; reg++) {
      int row = mb * 256 + wm * 64 + mt * 16 + q4 * 4 + reg;
      pmv[mt][reg] = (pm[row] != 0) ? 0.0f : 1.0f;
    }
#pragma unroll
  for (int nt = 0; nt < 6; nt++) {
    int cloc = wn * 96 + nt * 16 + m16;
    float bv = bias[nb * 192 + cloc];
#pragma unroll
    for (int mt = 0; mt < 4; mt++) {
#pragma unroll
      for (int reg = 0; reg < 4; reg++) {
        int rloc = wm * 64 + mt * 16 + q4 * 4 + reg;
        smem[rloc * CLP2 + cloc] = f2bf((acc[mt][nt][reg] + bv) * pmv[mt][reg]);
      }
    }
  }
  __syncthreads();
  const int s0 = mb * 256;                 // 256-row tiles never cross the 2048 batch boundary
  const int bh = (s0 >> 11) * 16 + nb, s0l = s0 & 2047;
  // q/k writeout: thread -> (row r of 256, 32-col half): 64 B q + 64 B k
  {
    int r = t >> 1, half = t & 1;
    const unsigned short* sq = &smem[r * CLP2 + half * 32];
    unsigned short* dq = qo + ((size_t)(bh * 2048 + s0l + r)) * 64 + half * 32;
#pragma unroll
    for (int j = 0; j < 4; j++)
      *reinterpret_cast<short8*>(dq + j * 8) = *reinterpret_cast<const short8*>(sq + j * 8);
    const unsigned short* sk = &smem[r * CLP2 + 64 + half * 32];
    unsigned short* dk = ko + ((size_t)(bh * 2048 + s0l + r)) * 64 + half * 32;
#pragma unroll
    for (int j = 0; j < 4; j++)
      *reinterpret_cast<short8*>(dk + j * 8) = *reinterpret_cast<const short8*>(sk + j * 8);
  }
  // vT writeout: thread -> (d = t&63, 32-row octant): 64 B contiguous in s
  {
    int d = t & 63, oct = t >> 6;
    unsigned short* dst = vTp + (size_t)(bh * 64 + d) * SP + 128 + s0l + oct * 32;
#pragma unroll
    for (int j8 = 0; j8 < 4; j8++) {
      short8 tmp;
#pragma unroll
      for (int jj = 0; jj < 8; jj++)
        tmp[jj] = (short)smem[(oct * 32 + j8 * 8 + jj) * CLP2 + 128 + d];
      *reinterpret_cast<short8*>(dst + j8 * 8) = tmp;
    }
  }
}

// ---------------- output projection: 64x128 tile, BK=64, dbuf + COUNTED vmcnt ----------------
// 512 blocks = 2/CU. Raw s_barrier pairs; no vmcnt(0) in main loop (T4).
__global__ __launch_bounds__(256) void gemm_out(
    const unsigned short* __restrict__ A, const unsigned short* __restrict__ Bm,
    const float* __restrict__ bias, float* __restrict__ out)
{
  // staging: 2 bufs x 12288 u16 = 49,152 B; epilogue Cldf [64][132] f32 aliased
  __shared__ __align__(16) unsigned char smemraw[49152];
  float* Cldf = (float*)smemraw;
  const int t = threadIdx.x, wave = t >> 6, lane = t & 63;
  const int m16 = lane & 15, q4 = lane >> 4;
  const int wm = wave >> 1, wn = wave & 1;                // 2x2 waves: 32 rows x 64 cols each
  const int flat = blockIdx.y * 8 + blockIdx.x;
  const int xcd = flat & 7, bi = flat >> 3;
  const int mb = xcd * 8 + (bi & 7);                      // per XCD: 8 mb x 8 nb
  const int nb = bi >> 3;
  const int srow = lane >> 2, scol = (lane & 3) << 3;
  const unsigned short* pA  = A + (size_t)(mb * 64 + wave * 16 + srow) * KDIM + scol;
  const unsigned short* pB0 = Bm + (size_t)(nb * 128 + wave * 32 + srow) * KDIM + scol;
  const unsigned short* pB1 = pB0 + 16 * KDIM;
  f32x4 acc[2][4];
#pragma unroll
  for (int i_ = 0; i_ < 2; i_++)
#pragma unroll
    for (int j_ = 0; j_ < 4; j_++) acc[i_][j_] = (f32x4){0.f, 0.f, 0.f, 0.f};

  auto stage = [&](int buf, int kt) {
    unsigned short* As = (unsigned short*)smemraw + buf * 12288;
    unsigned short* Bs = As + 4096;
#pragma unroll
    for (int h = 0; h < 2; h++) {
      gload_lds16(pA + kt + h * 32,  As + h * 2048 + (wave * 16) * 32);
      gload_lds16(pB0 + kt + h * 32, Bs + h * 4096 + (wave * 32) * 32);
      gload_lds16(pB1 + kt + h * 32, Bs + h * 4096 + (wave * 32 + 16) * 32);
    }
  };

  stage(0, 0);
  __builtin_amdgcn_sched_barrier(0);
  int cur = 0;
  for (int kt = 0; kt < KDIM; kt += 64) {
    const bool st = (kt + 64 < KDIM);
    if (st) stage(cur ^ 1, kt + 64);                      // 6 fresh loads
    __builtin_amdgcn_sched_barrier(0);
    if (st) asm volatile("s_waitcnt vmcnt(6)" ::: "memory");   // old slab landed, fresh in flight
    else    asm volatile("s_waitcnt vmcnt(0)" ::: "memory");
    __builtin_amdgcn_sched_barrier(0);
    __builtin_amdgcn_s_barrier();
    __builtin_amdgcn_sched_barrier(0);
    const unsigned short* As = (const unsigned short*)smemraw + cur * 12288;
    const unsigned short* Bs = As + 4096;
#pragma unroll
    for (int h = 0; h < 2; h++) {
      short8 af[2], bf[4];
#pragma unroll
      for (int mt = 0; mt < 2; mt++)
        af[mt] = *reinterpret_cast<const short8*>(&As[h * 2048 + (wm * 32 + mt * 16 + m16) * 32 + q4 * 8]);
#pragma unroll
      for (int nt = 0; nt < 4; nt++)
        bf[nt] = *reinterpret_cast<const short8*>(&Bs[h * 4096 + (wn * 64 + nt * 16 + m16) * 32 + q4 * 8]);
#pragma unroll
      for (int mt = 0; mt < 2; mt++)
#pragma unroll
        for (int nt = 0; nt < 4; nt++)
          acc[mt][nt] = __builtin_amdgcn_mfma_f32_16x16x32_bf16(af[mt], bf[nt], acc[mt][nt], 0, 0, 0);
    }
    __builtin_amdgcn_sched_barrier(0);
    __builtin_amdgcn_s_barrier();
    __builtin_amdgcn_sched_barrier(0);
    cur ^= 1;
  }

#pragma unroll
  for (int nt = 0; nt < 4; nt++) {
    int cloc = wn * 64 + nt * 16 + m16;
    float bv = bias[nb * 128 + cloc];
#pragma unroll
    for (int mt = 0; mt < 2; mt++) {
#pragma unroll
      for (int reg = 0; reg < 4; reg++) {
        int rloc = wm * 32 + mt * 16 + q4 * 4 + reg;
        Cldf[rloc * 132 + cloc] = acc[mt][nt][reg] + bv;
      }
    }
  }
  __syncthreads();
  {
    int r = t >> 2, seg = t & 3;   // 64 rows x 4 segments of 32 floats (128 B)
    float* dst = out + (size_t)(mb * 64 + r) * EMBED + nb * 128 + seg * 32;
    const float* srcl = &Cldf[r * 132 + seg * 32];
#pragma unroll
    for (int j = 0; j < 8; j++)
      *reinterpret_cast<float4*>(dst + j * 4) = *reinterpret_cast<const float4*>(srcl + j * 4);
  }
}

// ---------------- banded attention v4: NO K/V staging (L2-direct), zero barriers ----------------
// K/V working set per XCD (bh-fastest grid): 4 bh x (K 256KB + vT 292KB + q 256KB) ~ 3.2 MB
// < 4 MB L2, and K/vT were written by gemm_qkv on the SAME home XCD (nb%8 == bid%8).
// QK^T B-fragment = coalesced 1KB/instr over contiguous K rows; PV reads 64B chunks of vT.
// LDS holds only the wave-local P buffer -> no __syncthreads at all; 3 blocks/CU.
__global__ __launch_bounds__(256, 3) void attn_kernel(
    const unsigned short* __restrict__ q, const unsigned short* __restrict__ k,
    const unsigned short* __restrict__ vTp, unsigned short* __restrict__ vals)
{
  __shared__ __align__(16) unsigned short Pall[4 * 4736];   // 4 waves x [16][296] u16 = 37,888 B

  const int bid = blockIdx.x;
  const int bh = bid & 31, qg = bid >> 5;                // bh-fastest: XCD-local K/V
  const int lane = threadIdx.x & 63, wave = threadIdx.x >> 6;
  const int i0b = qg * 64;
  const int i0 = i0b + wave * 16;
  const int m16 = lane & 15, q4 = lane >> 4;

  const unsigned short* kbase = k + (size_t)bh * 2048 * 64;
  // q fragments (direct, tiny)
  const unsigned short* qb = q + ((size_t)(bh * 2048 + i0 + m16)) * 64 + q4 * 8;
  short8 aq0 = *reinterpret_cast<const short8*>(qb);
  short8 aq1 = *reinterpret_cast<const short8*>(qb + 32);

  // ---- QK^T + streaming exp, P packed in registers; K direct from L2 ----
  float sum[4] = {0.f, 0.f, 0.f, 0.f};
  uint32_t pP[18][2];
#pragma unroll
  for (int ct = 0; ct < 18; ct++) {
    int r = (wave + ct) * 16 + m16;
    int js = i0b - 128 + r;                    // global key index
    int grow = js < 0 ? 0 : (js > 2047 ? 2047 : js);   // clamped rows are masked below
    const unsigned short* kr = kbase + (size_t)grow * 64;
    short8 b0 = *reinterpret_cast<const short8*>(kr + q4 * 8);
    short8 b1 = *reinterpret_cast<const short8*>(kr + 32 + q4 * 8);
    f32x4 a = {0.f, 0.f, 0.f, 0.f};
    a = __builtin_amdgcn_mfma_f32_16x16x32_bf16(aq0, b0, a, 0, 0, 0);
    a = __builtin_amdgcn_mfma_f32_16x16x32_bf16(aq1, b1, a, 0, 0, 0);
    unsigned short pe[4];
#pragma unroll
    for (int reg = 0; reg < 4; reg++) {
      int i = i0 + q4 * 4 + reg;
      bool valid = (js >= 0) && (js < 2048) && (js >= i - 128) && (js <= i + 128);
      float e = valid ? __expf(a[reg] * 0.125f) : 0.0f;
      sum[reg] += e;
      pe[reg] = f2bf(e);
    }
    pP[ct][0] = (uint32_t)pe[0] | ((uint32_t)pe[1] << 16);
    pP[ct][1] = (uint32_t)pe[2] | ((uint32_t)pe[3] << 16);
  }
  float rden[4];
#pragma unroll
  for (int reg = 0; reg < 4; reg++) {
    float s = sum[reg];
    s += __shfl_xor(s, 1);
    s += __shfl_xor(s, 2);
    s += __shfl_xor(s, 4);
    s += __shfl_xor(s, 8);
    rden[reg] = 1.0f / s;
  }

  // ---- P -> LDS (wave-local; own-wave ordering via lgkmcnt, no barrier) ----
  unsigned short* Pw = Pall + wave * 4736;
#pragma unroll
  for (int ct = 0; ct < 18; ct++) {
    Pw[(q4 * 4 + 0) * 296 + ct * 16 + m16] = (unsigned short)(pP[ct][0] & 0xFFFF);
    Pw[(q4 * 4 + 1) * 296 + ct * 16 + m16] = (unsigned short)(pP[ct][0] >> 16);
    Pw[(q4 * 4 + 2) * 296 + ct * 16 + m16] = (unsigned short)(pP[ct][1] & 0xFFFF);
    Pw[(q4 * 4 + 3) * 296 + ct * 16 + m16] = (unsigned short)(pP[ct][1] >> 16);
  }
  short8 ap[9];
#pragma unroll
  for (int kc = 0; kc < 9; kc++)
    ap[kc] = *reinterpret_cast<const short8*>(&Pw[m16 * 296 + kc * 32 + q4 * 8]);

  // ---- PV: V^T direct from L2 (vTp halo-padded; col i0b+jseg*8+7 <= 2304 < SP) ----
  const unsigned short* vbase = vTp + (size_t)bh * 64 * SP + i0b;  // col(i0b) == key i0b-128
  const int b = bh >> 4, h = bh & 15;
#pragma unroll
  for (int dt = 0; dt < 4; dt++) {
    int vrow = dt * 16 + m16;
    const unsigned short* vr = vbase + (size_t)vrow * SP;
    f32x4 av = {0.f, 0.f, 0.f, 0.f};
#pragma unroll
    for (int kc = 0; kc < 9; kc++) {
      int jseg = kc * 4 + wave * 2 + q4;       // logical 16B seg within V^T row
      if (jseg > 39) jseg = 39;                // clamp: clamped segs have P==0
      short8 bv = *reinterpret_cast<const short8*>(vr + jseg * 8);
      av = __builtin_amdgcn_mfma_f32_16x16x32_bf16(ap[kc], bv, av, 0, 0, 0);
    }
#pragma unroll
    for (int reg = 0; reg < 4; reg++)
      Pw[(q4 * 4 + reg) * 296 + dt * 16 + m16] = f2bf(av[reg] * rden[reg]);
  }
  // coalesced O writeout: 4 lanes x 32B per row -> full 128B lines (wave-local rows)
  {
    int srow = lane >> 2, seg = lane & 3;
    unsigned short* dst = vals + ((size_t)(b * 2048 + i0 + srow)) * 1024 + h * 64 + seg * 16;
    const unsigned short* srcl = &Pw[srow * 296 + seg * 16];
    *reinterpret_cast<short8*>(dst)     = *reinterpret_cast<const short8*>(srcl);
    *reinterpret_cast<short8*>(dst + 8) = *reinterpret_cast<const short8*>(srcl + 8);
  }
}

extern "C" void kernel_launch(void* const* d_in, const int* in_sizes, int n_in,
                              void* d_out, int out_size, void* d_ws, size_t ws_size,
                              hipStream_t stream) {
  const float* x    = (const float*)d_in[0];
  const int*   pm   = (const int*)d_in[1];
  const float* Wqkv = (const float*)d_in[2];
  const float* bqkv = (const float*)d_in[3];
  const float* Wo   = (const float*)d_in[4];
  const float* bo   = (const float*)d_in[5];
  float* out = (float*)d_out;
  char* ws = (char*)d_ws;

  unsigned short* xb    = (unsigned short*)(ws);                 //  8,388,608
  unsigned short* vals  = (unsigned short*)(ws);                 //  reuse (xb dead after gemm_qkv)
  unsigned short* Wqkvb = (unsigned short*)(ws +  8388608);      //  6,291,456
  unsigned short* Wob   = (unsigned short*)(ws + 14680064);      //  2,097,152
  unsigned short* qbuf  = (unsigned short*)(ws + 16777216);      //  8,388,608
  unsigned short* kbuf  = (unsigned short*)(ws + 25165824);      //  8,388,608
  unsigned short* vTp   = (unsigned short*)(ws + 33554432);      //  9,568,256 (ends 43,122,688)

  cvt3_kernel<<<8768, 256, 0, stream>>>(x, Wqkv, Wo, xb, Wqkvb, Wob, vTp);
  gemm_qkv<<<256, 512, 0, stream>>>(xb, Wqkvb, bqkv, pm, qbuf, kbuf, vTp);
  attn_kernel<<<1024, 256, 0, stream>>>(qbuf, kbuf, vTp, vals);
  gemm_out<<<dim3(8, 64), 256, 0, stream>>>(vals, Wob, bo, out);
}

// Round 7
// 159.570 us; speedup vs baseline: 1.0574x; 1.0574x over previous
//
#include <hip/hip_runtime.h>
#include <stdint.h>

#define S_LEN 2048
#define EMBED 1024
#define HEADS 16
#define HD 64
#define M_ROWS 4096      // B*S
#define N_QKV 3072
#define KDIM 1024
#define SP 2336          // padded vT row length: 128 + 2048 + 160
#define CLP2 200         // qkv C-tile LDS col stride (u16)

typedef __attribute__((ext_vector_type(8))) short short8;
typedef __attribute__((ext_vector_type(4))) float f32x4;

__device__ __forceinline__ unsigned short f2bf(float f) {
  union { float f; uint32_t u; } c; c.f = f;
  uint32_t u = c.u;
  u += 0x7fffu + ((u >> 16) & 1u);  // round-to-nearest-even
  return (unsigned short)(u >> 16);
}

// async global->LDS, 16B per lane; lds base must be wave-uniform (HW adds lane*16)
__device__ __forceinline__ void gload_lds16(const unsigned short* g, unsigned short* l) {
  __builtin_amdgcn_global_load_lds(
      (const __attribute__((address_space(1))) void*)g,
      (__attribute__((address_space(3))) void*)l, 16, 0, 0);
}

// ---------------- fused fp32->bf16 convert (x, Wqkv, Wo) + vT halo zero ----------------
#define XQ 1048576
#define WQKVQ 786432
#define WOQ 262144
#define CVTQ (XQ + WQKVQ + WOQ)      // 2,097,152 quads
__global__ __launch_bounds__(256) void cvt3_kernel(
    const float* __restrict__ x, const float* __restrict__ wqkv, const float* __restrict__ wo,
    unsigned short* __restrict__ xb, unsigned short* __restrict__ wqkvb, unsigned short* __restrict__ wob,
    unsigned short* __restrict__ vTp) {
  int i = blockIdx.x * blockDim.x + threadIdx.x;
  if (i < CVTQ) {
    const float* s; unsigned short* d; int off;
    if (i < XQ)               { s = x;    d = xb;    off = i; }
    else if (i < XQ + WQKVQ)  { s = wqkv; d = wqkvb; off = i - XQ; }
    else                      { s = wo;   d = wob;   off = i - XQ - WQKVQ; }
    float4 f = reinterpret_cast<const float4*>(s)[off];
    ushort4 o;
    o.x = f2bf(f.x); o.y = f2bf(f.y); o.z = f2bf(f.z); o.w = f2bf(f.w);
    reinterpret_cast<ushort4*>(d)[off] = o;
  } else {
    int j = i - CVTQ;                      // 0..147455
    int row = j / 72, p = j % 72;          // row = bh*64+d
    int off = row * 584 + (p < 32 ? p : 544 + (p - 32));  // left 128 u16 / right 160 u16
    reinterpret_cast<ushort4*>(vTp)[off] = (ushort4){0, 0, 0, 0};
  }
}

// ---------------- QKV GEMM: 256x192 tile, BK=64, 4-phase + COUNTED vmcnt (T4) ----------------
// Round-3 best-measured version (159.1 us total). NO vmcnt(0) in the main loop: at P0 of
// tile T issue 3 fresh stage units then vmcnt(3) -> in-order retire guarantees the slab
// about to be read landed, fresh loads stay in flight. barrier after vmcnt, before ds_reads.
__global__ __launch_bounds__(512, 2) void gemm_qkv(
    const unsigned short* __restrict__ A, const unsigned short* __restrict__ Bm,
    const float* __restrict__ bias, const int* __restrict__ pm,
    unsigned short* __restrict__ qo, unsigned short* __restrict__ ko,
    unsigned short* __restrict__ vTp)
{
  // 2 slabs x (A 256x64 + B 192x64) u16 = 114,688 B; epilogue C [256][200] u16 aliased
  __shared__ __align__(16) unsigned short smem[57344];
  const int t = threadIdx.x, wave = t >> 6, lane = t & 63;
  const int m16 = lane & 15, q4 = lane >> 4;
  const int wm = wave >> 1, wn = wave & 1;          // 4x2 waves, each 64 rows x 96 cols
  const int bid = blockIdx.x;
  const int mb = bid >> 4, nb = bid & 15;           // bid%8 == nb%8 -> XCD affinity
  // staging: 56 units of 8 rows x 64k (1 KB); wave w owns units w*7..w*7+6
  const int lrow = lane >> 3;                        // row within unit
  const int lsegsw = ((lane & 7) ^ lrow) * 8;        // pre-swizzled global seg (u16 off)
  const unsigned short* gsrc[7];
#pragma unroll
  for (int j = 0; j < 7; j++) {
    int u = wave * 7 + j;
    gsrc[j] = (u < 32 ? A  + (size_t)(mb * 256 + u * 8 + lrow) * KDIM
                      : Bm + (size_t)(nb * 192 + (u - 32) * 8 + lrow) * KDIM)
              + lsegsw;
  }
  const int rsw = (m16 & 7) * 8;                     // read-side swizzle (u16 XOR)

  f32x4 acc[4][6];
#pragma unroll
  for (int i_ = 0; i_ < 4; i_++)
#pragma unroll
    for (int j_ = 0; j_ < 6; j_++) acc[i_][j_] = (f32x4){0.f, 0.f, 0.f, 0.f};

  auto LDA = [&](short8* af, const unsigned short* As, int h) {
#pragma unroll
    for (int mt = 0; mt < 4; mt++)
      af[mt] = *reinterpret_cast<const short8*>(
          &As[(wm * 64 + mt * 16 + m16) * 64 + (((h * 4 + q4) * 8) ^ rsw)]);
  };
  auto LDB3 = [&](short8* bf, const unsigned short* Bs, int h, int n0) {
#pragma unroll
    for (int nt = 0; nt < 3; nt++)
      bf[nt] = *reinterpret_cast<const short8*>(
          &Bs[(wn * 96 + (n0 + nt) * 16 + m16) * 64 + (((h * 4 + q4) * 8) ^ rsw)]);
  };
  auto MM3 = [&](short8* af, short8* bf, int n0) {
#pragma unroll
    for (int mt = 0; mt < 4; mt++)
#pragma unroll
      for (int nt = 0; nt < 3; nt++)
        acc[mt][n0 + nt] =
            __builtin_amdgcn_mfma_f32_16x16x32_bf16(af[mt], bf[nt], acc[mt][n0 + nt], 0, 0, 0);
  };

  // prologue: issue tile 0 -> slab 0 (no wait here; T=0 P0's vmcnt(3) is the guarantee)
#pragma unroll
  for (int j = 0; j < 7; j++)
    gload_lds16(gsrc[j], smem + (wave * 7 + j) * 512);
  __builtin_amdgcn_sched_barrier(0);

  for (int T = 0; T < 16; ++T) {
    const int c = T & 1;
    const unsigned short* As = smem + c * 28672;
    const unsigned short* Bs = As + 16384;
    unsigned short* nslab = smem + (c ^ 1) * 28672;
    const int nkt = (T + 1) * 64;
    const bool st = (T < 15);
    short8 af[4], bf[3];

    // ---- P0: stage 0-2; COUNTED vmcnt; barrier; ds_read af[h0]+bf[h0,0-2]; MFMA ----
    if (st) {
#pragma unroll
      for (int j = 0; j < 3; j++)
        gload_lds16(gsrc[j] + nkt, nslab + (wave * 7 + j) * 512);
    }
    __builtin_amdgcn_sched_barrier(0);
    if (st) asm volatile("s_waitcnt vmcnt(3)" ::: "memory");
    else    asm volatile("s_waitcnt vmcnt(0)" ::: "memory");
    __builtin_amdgcn_sched_barrier(0);
    __builtin_amdgcn_s_barrier();
    __builtin_amdgcn_sched_barrier(0);
    LDA(af, As, 0);
    LDB3(bf, Bs, 0, 0);
    asm volatile("s_waitcnt lgkmcnt(0)" ::: "memory");
    __builtin_amdgcn_sched_barrier(0);
    __builtin_amdgcn_s_setprio(1);
    MM3(af, bf, 0);
    __builtin_amdgcn_s_setprio(0);
    __builtin_amdgcn_sched_barrier(0);
    __builtin_amdgcn_s_barrier();
    __builtin_amdgcn_sched_barrier(0);

    // ---- P1: ds_read bf[h0,3-5]; stage 3-4; barrier; MFMA (af live from P0) ----
    LDB3(bf, Bs, 0, 3);
    if (st) {
#pragma unroll
      for (int j = 3; j < 5; j++)
        gload_lds16(gsrc[j] + nkt, nslab + (wave * 7 + j) * 512);
    }
    __builtin_amdgcn_sched_barrier(0);
    __builtin_amdgcn_s_barrier();
    asm volatile("s_waitcnt lgkmcnt(0)" ::: "memory");
    __builtin_amdgcn_sched_barrier(0);
    __builtin_amdgcn_s_setprio(1);
    MM3(af, bf, 3);
    __builtin_amdgcn_s_setprio(0);
    __builtin_amdgcn_sched_barrier(0);
    __builtin_amdgcn_s_barrier();
    __builtin_amdgcn_sched_barrier(0);

    // ---- P2: ds_read af[h1]+bf[h1,0-2]; stage 5-6; barrier; MFMA ----
    LDA(af, As, 1);
    LDB3(bf, Bs, 1, 0);
    if (st) {
#pragma unroll
      for (int j = 5; j < 7; j++)
        gload_lds16(gsrc[j] + nkt, nslab + (wave * 7 + j) * 512);
    }
    __builtin_amdgcn_sched_barrier(0);
    __builtin_amdgcn_s_barrier();
    asm volatile("s_waitcnt lgkmcnt(0)" ::: "memory");
    __builtin_amdgcn_sched_barrier(0);
    __builtin_amdgcn_s_setprio(1);
    MM3(af, bf, 0);
    __builtin_amdgcn_s_setprio(0);
    __builtin_amdgcn_sched_barrier(0);
    __builtin_amdgcn_s_barrier();
    __builtin_amdgcn_sched_barrier(0);

    // ---- P3: ds_read bf[h1,3-5]; barrier; MFMA (NO vmcnt here - T4) ----
    LDB3(bf, Bs, 1, 3);
    __builtin_amdgcn_sched_barrier(0);
    __builtin_amdgcn_s_barrier();
    asm volatile("s_waitcnt lgkmcnt(0)" ::: "memory");
    __builtin_amdgcn_sched_barrier(0);
    __builtin_amdgcn_s_setprio(1);
    MM3(af, bf, 3);
    __builtin_amdgcn_s_setprio(0);
    __builtin_amdgcn_sched_barrier(0);
    __builtin_amdgcn_s_barrier();
    __builtin_amdgcn_sched_barrier(0);
  }

  // ---- epilogue: C via LDS [256][CLP2], then q/k/vT writeout ----
  float pmv[4][4];
#pragma unroll
  for (int mt = 0; mt < 4; mt++)
#pragma unroll
    for (int reg = 0; reg < 4; reg++) {
      int row = mb * 256 + wm * 64 + mt * 16 + q4 * 4 + reg;
      pmv[mt][reg] = (pm[row] != 0) ? 0.0f : 1.0f;
    }
#pragma unroll
  for (int nt = 0; nt < 6; nt++) {
    int cloc = wn * 96 + nt * 16 + m16;
    float bv = bias[nb * 192 + cloc];
#pragma unroll
    for (int mt = 0; mt < 4; mt++) {
#pragma unroll
      for (int reg = 0; reg < 4; reg++) {
        int rloc = wm * 64 + mt * 16 + q4 * 4 + reg;
        smem[rloc * CLP2 + cloc] = f2bf((acc[mt][nt][reg] + bv) * pmv[mt][reg]);
      }
    }
  }
  __syncthreads();
  const int s0 = mb * 256;                 // 256-row tiles never cross the 2048 batch boundary
  const int bh = (s0 >> 11) * 16 + nb, s0l = s0 & 2047;
  // q/k writeout: thread -> (row r of 256, 32-col half): 64 B q + 64 B k
  {
    int r = t >> 1, half = t & 1;
    const unsigned short* sq = &smem[r * CLP2 + half * 32];
    unsigned short* dq = qo + ((size_t)(bh * 2048 + s0l + r)) * 64 + half * 32;
#pragma unroll
    for (int j = 0; j < 4; j++)
      *reinterpret_cast<short8*>(dq + j * 8) = *reinterpret_cast<const short8*>(sq + j * 8);
    const unsigned short* sk = &smem[r * CLP2 + 64 + half * 32];
    unsigned short* dk = ko + ((size_t)(bh * 2048 + s0l + r)) * 64 + half * 32;
#pragma unroll
    for (int j = 0; j < 4; j++)
      *reinterpret_cast<short8*>(dk + j * 8) = *reinterpret_cast<const short8*>(sk + j * 8);
  }
  // vT writeout: thread -> (d = t&63, 32-row octant): 64 B contiguous in s
  {
    int d = t & 63, oct = t >> 6;
    unsigned short* dst = vTp + (size_t)(bh * 64 + d) * SP + 128 + s0l + oct * 32;
#pragma unroll
    for (int j8 = 0; j8 < 4; j8++) {
      short8 tmp;
#pragma unroll
      for (int jj = 0; jj < 8; jj++)
        tmp[jj] = (short)smem[(oct * 32 + j8 * 8 + jj) * CLP2 + 128 + d];
      *reinterpret_cast<short8*>(dst + j8 * 8) = tmp;
    }
  }
}

// ---------------- output projection: 64x128 tile, BK=64, dbuf + COUNTED vmcnt ----------------
// 512 blocks = 2/CU. Raw s_barrier pairs; no vmcnt(0) in main loop (T4).
__global__ __launch_bounds__(256) void gemm_out(
    const unsigned short* __restrict__ A, const unsigned short* __restrict__ Bm,
    const float* __restrict__ bias, float* __restrict__ out)
{
  // staging: 2 bufs x 12288 u16 = 49,152 B; epilogue Cldf [64][132] f32 aliased
  __shared__ __align__(16) unsigned char smemraw[49152];
  float* Cldf = (float*)smemraw;
  const int t = threadIdx.x, wave = t >> 6, lane = t & 63;
  const int m16 = lane & 15, q4 = lane >> 4;
  const int wm = wave >> 1, wn = wave & 1;                // 2x2 waves: 32 rows x 64 cols each
  const int flat = blockIdx.y * 8 + blockIdx.x;
  const int xcd = flat & 7, bi = flat >> 3;
  const int mb = xcd * 8 + (bi & 7);                      // per XCD: 8 mb x 8 nb
  const int nb = bi >> 3;
  const int srow = lane >> 2, scol = (lane & 3) << 3;
  const unsigned short* pA  = A + (size_t)(mb * 64 + wave * 16 + srow) * KDIM + scol;
  const unsigned short* pB0 = Bm + (size_t)(nb * 128 + wave * 32 + srow) * KDIM + scol;
  const unsigned short* pB1 = pB0 + 16 * KDIM;
  f32x4 acc[2][4];
#pragma unroll
  for (int i_ = 0; i_ < 2; i_++)
#pragma unroll
    for (int j_ = 0; j_ < 4; j_++) acc[i_][j_] = (f32x4){0.f, 0.f, 0.f, 0.f};

  auto stage = [&](int buf, int kt) {
    unsigned short* As = (unsigned short*)smemraw + buf * 12288;
    unsigned short* Bs = As + 4096;
#pragma unroll
    for (int h = 0; h < 2; h++) {
      gload_lds16(pA + kt + h * 32,  As + h * 2048 + (wave * 16) * 32);
      gload_lds16(pB0 + kt + h * 32, Bs + h * 4096 + (wave * 32) * 32);
      gload_lds16(pB1 + kt + h * 32, Bs + h * 4096 + (wave * 32 + 16) * 32);
    }
  };

  stage(0, 0);
  __builtin_amdgcn_sched_barrier(0);
  int cur = 0;
  for (int kt = 0; kt < KDIM; kt += 64) {
    const bool st = (kt + 64 < KDIM);
    if (st) stage(cur ^ 1, kt + 64);                      // 6 fresh loads
    __builtin_amdgcn_sched_barrier(0);
    if (st) asm volatile("s_waitcnt vmcnt(6)" ::: "memory");   // old slab landed, fresh in flight
    else    asm volatile("s_waitcnt vmcnt(0)" ::: "memory");
    __builtin_amdgcn_sched_barrier(0);
    __builtin_amdgcn_s_barrier();
    __builtin_amdgcn_sched_barrier(0);
    const unsigned short* As = (const unsigned short*)smemraw + cur * 12288;
    const unsigned short* Bs = As + 4096;
#pragma unroll
    for (int h = 0; h < 2; h++) {
      short8 af[2], bf[4];
#pragma unroll
      for (int mt = 0; mt < 2; mt++)
        af[mt] = *reinterpret_cast<const short8*>(&As[h * 2048 + (wm * 32 + mt * 16 + m16) * 32 + q4 * 8]);
#pragma unroll
      for (int nt = 0; nt < 4; nt++)
        bf[nt] = *reinterpret_cast<const short8*>(&Bs[h * 4096 + (wn * 64 + nt * 16 + m16) * 32 + q4 * 8]);
#pragma unroll
      for (int mt = 0; mt < 2; mt++)
#pragma unroll
        for (int nt = 0; nt < 4; nt++)
          acc[mt][nt] = __builtin_amdgcn_mfma_f32_16x16x32_bf16(af[mt], bf[nt], acc[mt][nt], 0, 0, 0);
    }
    __builtin_amdgcn_sched_barrier(0);
    __builtin_amdgcn_s_barrier();
    __builtin_amdgcn_sched_barrier(0);
    cur ^= 1;
  }

#pragma unroll
  for (int nt = 0; nt < 4; nt++) {
    int cloc = wn * 64 + nt * 16 + m16;
    float bv = bias[nb * 128 + cloc];
#pragma unroll
    for (int mt = 0; mt < 2; mt++) {
#pragma unroll
      for (int reg = 0; reg < 4; reg++) {
        int rloc = wm * 32 + mt * 16 + q4 * 4 + reg;
        Cldf[rloc * 132 + cloc] = acc[mt][nt][reg] + bv;
      }
    }
  }
  __syncthreads();
  {
    int r = t >> 2, seg = t & 3;   // 64 rows x 4 segments of 32 floats (128 B)
    float* dst = out + (size_t)(mb * 64 + r) * EMBED + nb * 128 + seg * 32;
    const float* srcl = &Cldf[r * 132 + seg * 32];
#pragma unroll
    for (int j = 0; j < 8; j++)
      *reinterpret_cast<float4*>(dst + j * 4) = *reinterpret_cast<const float4*>(srcl + j * 4);
  }
}

// ---------------- banded attention v5: staged K/V, split-wait (T4) ----------------
// v3 + counted vmcnt: issue q(2), K units(10), V units(10); wait vmcnt(10) -> q+K landed,
// V's 40 KB stays in flight under the QK^T+softmax phase (>2000 cyc); the mid-kernel
// __syncthreads (implicit vmcnt(0)) lands V block-wide exactly where PV needs it.
__global__ __launch_bounds__(256, 2) void attn_kernel(
    const unsigned short* __restrict__ q, const unsigned short* __restrict__ k,
    const unsigned short* __restrict__ vTp, unsigned short* __restrict__ vals)
{
  __shared__ __align__(16) unsigned short smem[40960];   // 81,920 B
  unsigned short* Ks = smem;            // [320][64] u16 (40,960 B)
  unsigned short* Vs = smem + 20480;    // [64][320] u16 (40,960 B)
  unsigned short* Pld = smem;           // alias over Ks after QK phase: [4][16][296]

  const int bid = blockIdx.x;
  const int bh = bid & 31, qg = bid >> 5;                // bh-fastest: XCD-local K/V
  const int lane = threadIdx.x & 63, wave = threadIdx.x >> 6;
  const int i0b = qg * 64;
  const int i0 = i0b + wave * 16;
  const int m16 = lane & 15, q4 = lane >> 4;

  // ---- q fragments FIRST (oldest in vmcnt queue; retired by the vmcnt(10) wait) ----
  const unsigned short* qb = q + ((size_t)(bh * 2048 + i0 + m16)) * 64 + q4 * 8;
  short8 aq0 = *reinterpret_cast<const short8*>(qb);
  short8 aq1 = *reinterpret_cast<const short8*>(qb + 32);
  __builtin_amdgcn_sched_barrier(0);

  // ---- stage K window: 40 KB = 10 wave-issues of 1 KB per wave ----
  const unsigned short* kbase = k + (size_t)bh * 2048 * 64;
#pragma unroll
  for (int n = 0; n < 10; n++) {
    int idx = (n * 4 + wave) * 64 + lane;      // 0..2559
    int krow = idx >> 3, seg = idx & 7;
    int grow = i0b - 128 + krow;
    grow = grow < 0 ? 0 : (grow > 2047 ? 2047 : grow);
    int lseg = seg ^ (krow & 7);               // store swizzled within 128B row
    gload_lds16(kbase + (size_t)grow * 64 + lseg * 8, Ks + (n * 4 + wave) * 512);
  }
  __builtin_amdgcn_sched_barrier(0);
  // ---- stage V^T window: 40 KB, rows of 320 u16 (40 segs of 16B) ----
  const unsigned short* vbase = vTp + (size_t)bh * 64 * SP + i0b;  // col(i0b) == key i0b-128
#pragma unroll
  for (int n = 0; n < 10; n++) {
    int idx = (n * 4 + wave) * 64 + lane;      // 0..2559
    int vrow = idx / 40, rem = idx % 40;
    int l = (rem & ~7) | ((rem & 7) ^ (vrow & 7));
    gload_lds16(vbase + (size_t)vrow * SP + l * 8, Vs + (n * 4 + wave) * 512);
  }
  __builtin_amdgcn_sched_barrier(0);

  // counted wait: q(2)+K(10) retired, V(10) in flight; raw barrier (no drain)
  asm volatile("s_waitcnt vmcnt(10)" ::: "memory");
  __builtin_amdgcn_sched_barrier(0);
  __builtin_amdgcn_s_barrier();
  __builtin_amdgcn_sched_barrier(0);

  // ---- QK^T + streaming exp, P packed in registers (V still landing underneath) ----
  float sum[4] = {0.f, 0.f, 0.f, 0.f};
  uint32_t pP[18][2];
#pragma unroll
  for (int ct = 0; ct < 18; ct++) {
    int r = (wave + ct) * 16 + m16;            // LDS key row (may run past 320: finite data, masked)
    int js = i0b - 128 + r;                    // global key index
    const unsigned short* kr = Ks + r * 64;
    short8 b0 = *reinterpret_cast<const short8*>(kr + ((q4 ^ (r & 7)) * 8));
    short8 b1 = *reinterpret_cast<const short8*>(kr + (((q4 + 4) ^ (r & 7)) * 8));
    f32x4 a = {0.f, 0.f, 0.f, 0.f};
    a = __builtin_amdgcn_mfma_f32_16x16x32_bf16(aq0, b0, a, 0, 0, 0);
    a = __builtin_amdgcn_mfma_f32_16x16x32_bf16(aq1, b1, a, 0, 0, 0);
    unsigned short pe[4];
#pragma unroll
    for (int reg = 0; reg < 4; reg++) {
      int i = i0 + q4 * 4 + reg;
      bool valid = (js >= 0) && (js < 2048) && (js >= i - 128) && (js <= i + 128);
      float e = valid ? __expf(a[reg] * 0.125f) : 0.0f;
      sum[reg] += e;
      pe[reg] = f2bf(e);
    }
    pP[ct][0] = (uint32_t)pe[0] | ((uint32_t)pe[1] << 16);
    pP[ct][1] = (uint32_t)pe[2] | ((uint32_t)pe[3] << 16);
  }
  float rden[4];
#pragma unroll
  for (int reg = 0; reg < 4; reg++) {
    float s = sum[reg];
    s += __shfl_xor(s, 1);
    s += __shfl_xor(s, 2);
    s += __shfl_xor(s, 4);
    s += __shfl_xor(s, 8);
    rden[reg] = 1.0f / s;
  }

  __syncthreads();   // implicit vmcnt(0): V landed block-wide; Ks reads done -> Pld may overwrite

  unsigned short* Pw = Pld + wave * 16 * 296;
#pragma unroll
  for (int ct = 0; ct < 18; ct++) {
    Pw[(q4 * 4 + 0) * 296 + ct * 16 + m16] = (unsigned short)(pP[ct][0] & 0xFFFF);
    Pw[(q4 * 4 + 1) * 296 + ct * 16 + m16] = (unsigned short)(pP[ct][0] >> 16);
    Pw[(q4 * 4 + 2) * 296 + ct * 16 + m16] = (unsigned short)(pP[ct][1] & 0xFFFF);
    Pw[(q4 * 4 + 3) * 296 + ct * 16 + m16] = (unsigned short)(pP[ct][1] >> 16);
  }
  // own-wave LDS ordering handled by lgkmcnt; no block barrier needed
  short8 ap[9];
#pragma unroll
  for (int kc = 0; kc < 9; kc++)
    ap[kc] = *reinterpret_cast<const short8*>(&Pw[m16 * 296 + kc * 32 + q4 * 8]);

  const int b = bh >> 4, h = bh & 15;
#pragma unroll
  for (int dt = 0; dt < 4; dt++) {
    int vrow = dt * 16 + m16;
    const unsigned short* vr = Vs + vrow * 320;
    f32x4 av = {0.f, 0.f, 0.f, 0.f};
#pragma unroll
    for (int kc = 0; kc < 9; kc++) {
      int jseg = kc * 4 + wave * 2 + q4;       // logical 16B seg within V^T row
      if (jseg > 39) jseg = 39;                // clamp: clamped segs have P==0
      int sseg = (jseg & ~7) | ((jseg & 7) ^ (vrow & 7));
      short8 bv = *reinterpret_cast<const short8*>(vr + sseg * 8);
      av = __builtin_amdgcn_mfma_f32_16x16x32_bf16(ap[kc], bv, av, 0, 0, 0);
    }
#pragma unroll
    for (int reg = 0; reg < 4; reg++)
      Pw[(q4 * 4 + reg) * 296 + dt * 16 + m16] = f2bf(av[reg] * rden[reg]);
  }
  // coalesced O writeout: 4 lanes x 32B per row -> full 128B lines
  {
    int srow = lane >> 2, seg = lane & 3;
    unsigned short* dst = vals + ((size_t)(b * 2048 + i0 + srow)) * 1024 + h * 64 + seg * 16;
    const unsigned short* srcl = &Pw[srow * 296 + seg * 16];
    *reinterpret_cast<short8*>(dst)     = *reinterpret_cast<const short8*>(srcl);
    *reinterpret_cast<short8*>(dst + 8) = *reinterpret_cast<const short8*>(srcl + 8);
  }
}

extern "C" void kernel_launch(void* const* d_in, const int* in_sizes, int n_in,
                              void* d_out, int out_size, void* d_ws, size_t ws_size,
                              hipStream_t stream) {
  const float* x    = (const float*)d_in[0];
  const int*   pm   = (const int*)d_in[1];
  const float* Wqkv = (const float*)d_in[2];
  const float* bqkv = (const float*)d_in[3];
  const float* Wo   = (const float*)d_in[4];
  const float* bo   = (const float*)d_in[5];
  float* out = (float*)d_out;
  char* ws = (char*)d_ws;

  unsigned short* xb    = (unsigned short*)(ws);                 //  8,388,608
  unsigned short* vals  = (unsigned short*)(ws);                 //  reuse (xb dead after gemm_qkv)
  unsigned short* Wqkvb = (unsigned short*)(ws +  8388608);      //  6,291,456
  unsigned short* Wob   = (unsigned short*)(ws + 14680064);      //  2,097,152
  unsigned short* qbuf  = (unsigned short*)(ws + 16777216);      //  8,388,608
  unsigned short* kbuf  = (unsigned short*)(ws + 25165824);      //  8,388,608
  unsigned short* vTp   = (unsigned short*)(ws + 33554432);      //  9,568,256 (ends 43,122,688)

  cvt3_kernel<<<8768, 256, 0, stream>>>(x, Wqkv, Wo, xb, Wqkvb, Wob, vTp);
  gemm_qkv<<<256, 512, 0, stream>>>(xb, Wqkvb, bqkv, pm, qbuf, kbuf, vTp);
  attn_kernel<<<1024, 256, 0, stream>>>(qbuf, kbuf, vTp, vals);
  gemm_out<<<dim3(8, 64), 256, 0, stream>>>(vals, Wob, bo, out);
}

// Round 9
// 158.973 us; speedup vs baseline: 1.0614x; 1.0038x over previous
//
#include <hip/hip_runtime.h>
#include <stdint.h>

#define S_LEN 2048
#define EMBED 1024
#define HEADS 16
#define HD 64
#define M_ROWS 4096      // B*S
#define N_QKV 3072
#define KDIM 1024
#define SP 2336          // padded vT row length: 128 + 2048 + 160
#define CLP2 200         // qkv C-tile LDS col stride (u16)

typedef __attribute__((ext_vector_type(8))) short short8;
typedef __attribute__((ext_vector_type(4))) float f32x4;

__device__ __forceinline__ unsigned short f2bf(float f) {
  union { float f; uint32_t u; } c; c.f = f;
  uint32_t u = c.u;
  u += 0x7fffu + ((u >> 16) & 1u);  // round-to-nearest-even
  return (unsigned short)(u >> 16);
}

// async global->LDS, 16B per lane; lds base must be wave-uniform (HW adds lane*16)
__device__ __forceinline__ void gload_lds16(const unsigned short* g, unsigned short* l) {
  __builtin_amdgcn_global_load_lds(
      (const __attribute__((address_space(1))) void*)g,
      (__attribute__((address_space(3))) void*)l, 16, 0, 0);
}

// ---------------- fused fp32->bf16 convert (x, Wqkv, Wo) + vT halo zero ----------------
#define XQ 1048576
#define WQKVQ 786432
#define WOQ 262144
#define CVTQ (XQ + WQKVQ + WOQ)      // 2,097,152 quads
__global__ __launch_bounds__(256) void cvt3_kernel(
    const float* __restrict__ x, const float* __restrict__ wqkv, const float* __restrict__ wo,
    unsigned short* __restrict__ xb, unsigned short* __restrict__ wqkvb, unsigned short* __restrict__ wob,
    unsigned short* __restrict__ vTp) {
  int i = blockIdx.x * blockDim.x + threadIdx.x;
  if (i < CVTQ) {
    const float* s; unsigned short* d; int off;
    if (i < XQ)               { s = x;    d = xb;    off = i; }
    else if (i < XQ + WQKVQ)  { s = wqkv; d = wqkvb; off = i - XQ; }
    else                      { s = wo;   d = wob;   off = i - XQ - WQKVQ; }
    float4 f = reinterpret_cast<const float4*>(s)[off];
    ushort4 o;
    o.x = f2bf(f.x); o.y = f2bf(f.y); o.z = f2bf(f.z); o.w = f2bf(f.w);
    reinterpret_cast<ushort4*>(d)[off] = o;
  } else {
    int j = i - CVTQ;                      // 0..147455
    int row = j / 72, p = j % 72;          // row = bh*64+d
    int off = row * 584 + (p < 32 ? p : 544 + (p - 32));  // left 128 u16 / right 160 u16
    reinterpret_cast<ushort4*>(vTp)[off] = (ushort4){0, 0, 0, 0};
  }
}

// ---------------- QKV GEMM: 256x192 tile, BK=64, 4-phase + COUNTED vmcnt (T4) ----------------
// Round-3 best-measured version. NO vmcnt(0) in the main loop: at P0 of tile T issue 3
// fresh stage units then vmcnt(3) -> in-order retire guarantees the slab about to be read
// landed, fresh loads stay in flight. barrier after vmcnt, before ds_reads.
__global__ __launch_bounds__(512, 2) void gemm_qkv(
    const unsigned short* __restrict__ A, const unsigned short* __restrict__ Bm,
    const float* __restrict__ bias, const int* __restrict__ pm,
    unsigned short* __restrict__ qo, unsigned short* __restrict__ ko,
    unsigned short* __restrict__ vTp)
{
  // 2 slabs x (A 256x64 + B 192x64) u16 = 114,688 B; epilogue C [256][200] u16 aliased
  __shared__ __align__(16) unsigned short smem[57344];
  const int t = threadIdx.x, wave = t >> 6, lane = t & 63;
  const int m16 = lane & 15, q4 = lane >> 4;
  const int wm = wave >> 1, wn = wave & 1;          // 4x2 waves, each 64 rows x 96 cols
  const int bid = blockIdx.x;
  const int mb = bid >> 4, nb = bid & 15;           // bid%8 == nb%8 -> XCD affinity
  // staging: 56 units of 8 rows x 64k (1 KB); wave w owns units w*7..w*7+6
  const int lrow = lane >> 3;                        // row within unit
  const int lsegsw = ((lane & 7) ^ lrow) * 8;        // pre-swizzled global seg (u16 off)
  const unsigned short* gsrc[7];
#pragma unroll
  for (int j = 0; j < 7; j++) {
    int u = wave * 7 + j;
    gsrc[j] = (u < 32 ? A  + (size_t)(mb * 256 + u * 8 + lrow) * KDIM
                      : Bm + (size_t)(nb * 192 + (u - 32) * 8 + lrow) * KDIM)
              + lsegsw;
  }
  const int rsw = (m16 & 7) * 8;                     // read-side swizzle (u16 XOR)

  f32x4 acc[4][6];
#pragma unroll
  for (int i_ = 0; i_ < 4; i_++)
#pragma unroll
    for (int j_ = 0; j_ < 6; j_++) acc[i_][j_] = (f32x4){0.f, 0.f, 0.f, 0.f};

  auto LDA = [&](short8* af, const unsigned short* As, int h) {
#pragma unroll
    for (int mt = 0; mt < 4; mt++)
      af[mt] = *reinterpret_cast<const short8*>(
          &As[(wm * 64 + mt * 16 + m16) * 64 + (((h * 4 + q4) * 8) ^ rsw)]);
  };
  auto LDB3 = [&](short8* bf, const unsigned short* Bs, int h, int n0) {
#pragma unroll
    for (int nt = 0; nt < 3; nt++)
      bf[nt] = *reinterpret_cast<const short8*>(
          &Bs[(wn * 96 + (n0 + nt) * 16 + m16) * 64 + (((h * 4 + q4) * 8) ^ rsw)]);
  };
  auto MM3 = [&](short8* af, short8* bf, int n0) {
#pragma unroll
    for (int mt = 0; mt < 4; mt++)
#pragma unroll
      for (int nt = 0; nt < 3; nt++)
        acc[mt][n0 + nt] =
            __builtin_amdgcn_mfma_f32_16x16x32_bf16(af[mt], bf[nt], acc[mt][n0 + nt], 0, 0, 0);
  };

  // prologue: issue tile 0 -> slab 0 (no wait here; T=0 P0's vmcnt(3) is the guarantee)
#pragma unroll
  for (int j = 0; j < 7; j++)
    gload_lds16(gsrc[j], smem + (wave * 7 + j) * 512);
  __builtin_amdgcn_sched_barrier(0);

  for (int T = 0; T < 16; ++T) {
    const int c = T & 1;
    const unsigned short* As = smem + c * 28672;
    const unsigned short* Bs = As + 16384;
    unsigned short* nslab = smem + (c ^ 1) * 28672;
    const int nkt = (T + 1) * 64;
    const bool st = (T < 15);
    short8 af[4], bf[3];

    // ---- P0: stage 0-2; COUNTED vmcnt; barrier; ds_read af[h0]+bf[h0,0-2]; MFMA ----
    if (st) {
#pragma unroll
      for (int j = 0; j < 3; j++)
        gload_lds16(gsrc[j] + nkt, nslab + (wave * 7 + j) * 512);
    }
    __builtin_amdgcn_sched_barrier(0);
    if (st) asm volatile("s_waitcnt vmcnt(3)" ::: "memory");
    else    asm volatile("s_waitcnt vmcnt(0)" ::: "memory");
    __builtin_amdgcn_sched_barrier(0);
    __builtin_amdgcn_s_barrier();
    __builtin_amdgcn_sched_barrier(0);
    LDA(af, As, 0);
    LDB3(bf, Bs, 0, 0);
    asm volatile("s_waitcnt lgkmcnt(0)" ::: "memory");
    __builtin_amdgcn_sched_barrier(0);
    __builtin_amdgcn_s_setprio(1);
    MM3(af, bf, 0);
    __builtin_amdgcn_s_setprio(0);
    __builtin_amdgcn_sched_barrier(0);
    __builtin_amdgcn_s_barrier();
    __builtin_amdgcn_sched_barrier(0);

    // ---- P1: ds_read bf[h0,3-5]; stage 3-4; barrier; MFMA (af live from P0) ----
    LDB3(bf, Bs, 0, 3);
    if (st) {
#pragma unroll
      for (int j = 3; j < 5; j++)
        gload_lds16(gsrc[j] + nkt, nslab + (wave * 7 + j) * 512);
    }
    __builtin_amdgcn_sched_barrier(0);
    __builtin_amdgcn_s_barrier();
    asm volatile("s_waitcnt lgkmcnt(0)" ::: "memory");
    __builtin_amdgcn_sched_barrier(0);
    __builtin_amdgcn_s_setprio(1);
    MM3(af, bf, 3);
    __builtin_amdgcn_s_setprio(0);
    __builtin_amdgcn_sched_barrier(0);
    __builtin_amdgcn_s_barrier();
    __builtin_amdgcn_sched_barrier(0);

    // ---- P2: ds_read af[h1]+bf[h1,0-2]; stage 5-6; barrier; MFMA ----
    LDA(af, As, 1);
    LDB3(bf, Bs, 1, 0);
    if (st) {
#pragma unroll
      for (int j = 5; j < 7; j++)
        gload_lds16(gsrc[j] + nkt, nslab + (wave * 7 + j) * 512);
    }
    __builtin_amdgcn_sched_barrier(0);
    __builtin_amdgcn_s_barrier();
    asm volatile("s_waitcnt lgkmcnt(0)" ::: "memory");
    __builtin_amdgcn_sched_barrier(0);
    __builtin_amdgcn_s_setprio(1);
    MM3(af, bf, 0);
    __builtin_amdgcn_s_setprio(0);
    __builtin_amdgcn_sched_barrier(0);
    __builtin_amdgcn_s_barrier();
    __builtin_amdgcn_sched_barrier(0);

    // ---- P3: ds_read bf[h1,3-5]; barrier; MFMA (NO vmcnt here - T4) ----
    LDB3(bf, Bs, 1, 3);
    __builtin_amdgcn_sched_barrier(0);
    __builtin_amdgcn_s_barrier();
    asm volatile("s_waitcnt lgkmcnt(0)" ::: "memory");
    __builtin_amdgcn_sched_barrier(0);
    __builtin_amdgcn_s_setprio(1);
    MM3(af, bf, 3);
    __builtin_amdgcn_s_setprio(0);
    __builtin_amdgcn_sched_barrier(0);
    __builtin_amdgcn_s_barrier();
    __builtin_amdgcn_sched_barrier(0);
  }

  // ---- epilogue: C via LDS [256][CLP2], then q/k/vT writeout ----
  float pmv[4][4];
#pragma unroll
  for (int mt = 0; mt < 4; mt++)
#pragma unroll
    for (int reg = 0; reg < 4; reg++) {
      int row = mb * 256 + wm * 64 + mt * 16 + q4 * 4 + reg;
      pmv[mt][reg] = (pm[row] != 0) ? 0.0f : 1.0f;
    }
#pragma unroll
  for (int nt = 0; nt < 6; nt++) {
    int cloc = wn * 96 + nt * 16 + m16;
    float bv = bias[nb * 192 + cloc];
#pragma unroll
    for (int mt = 0; mt < 4; mt++) {
#pragma unroll
      for (int reg = 0; reg < 4; reg++) {
        int rloc = wm * 64 + mt * 16 + q4 * 4 + reg;
        smem[rloc * CLP2 + cloc] = f2bf((acc[mt][nt][reg] + bv) * pmv[mt][reg]);
      }
    }
  }
  __syncthreads();
  const int s0 = mb * 256;                 // 256-row tiles never cross the 2048 batch boundary
  const int bh = (s0 >> 11) * 16 + nb, s0l = s0 & 2047;
  // q/k writeout: thread -> (row r of 256, 32-col half): 64 B q + 64 B k
  {
    int r = t >> 1, half = t & 1;
    const unsigned short* sq = &smem[r * CLP2 + half * 32];
    unsigned short* dq = qo + ((size_t)(bh * 2048 + s0l + r)) * 64 + half * 32;
#pragma unroll
    for (int j = 0; j < 4; j++)
      *reinterpret_cast<short8*>(dq + j * 8) = *reinterpret_cast<const short8*>(sq + j * 8);
    const unsigned short* sk = &smem[r * CLP2 + 64 + half * 32];
    unsigned short* dk = ko + ((size_t)(bh * 2048 + s0l + r)) * 64 + half * 32;
#pragma unroll
    for (int j = 0; j < 4; j++)
      *reinterpret_cast<short8*>(dk + j * 8) = *reinterpret_cast<const short8*>(sk + j * 8);
  }
  // vT writeout: thread -> (d = t&63, 32-row octant): 64 B contiguous in s
  {
    int d = t & 63, oct = t >> 6;
    unsigned short* dst = vTp + (size_t)(bh * 64 + d) * SP + 128 + s0l + oct * 32;
#pragma unroll
    for (int j8 = 0; j8 < 4; j8++) {
      short8 tmp;
#pragma unroll
      for (int jj = 0; jj < 8; jj++)
        tmp[jj] = (short)smem[(oct * 32 + j8 * 8 + jj) * CLP2 + 128 + d];
      *reinterpret_cast<short8*>(dst + j8 * 8) = tmp;
    }
  }
}

// ---------------- output projection v2: 128x128 tile, BK=64, gemm_qkv-r3 structure ----------------
// 256 blocks (32 mb x 8 nb), nb = bid&7 = XCD -> each XCD's 256 KB Wo panel is L2-local,
// read 32x from L2. 256 thr = 4 waves (2x2), wave 64x64, acc 4x4 (read:MFMA 0.5 vs old 0.75).
// T4 counted vmcnt: issue 8 units -> vmcnt(8) -> barrier -> ds_read+MFMA -> barrier.
// XOR-seg swizzle identical to gemm_qkv (store pre-swizzled global src, read ^rsw).
__global__ __launch_bounds__(256) void gemm_out(
    const unsigned short* __restrict__ A, const unsigned short* __restrict__ Bm,
    const float* __restrict__ bias, float* __restrict__ out)
{
  // 2 slabs x (A 128x64 + B 128x64) u16 = 65,536 B; epilogue Cldf[128][132] f32 = 67,584 B
  __shared__ __align__(16) unsigned char smemraw[67584];
  unsigned short* smem = (unsigned short*)smemraw;
  float* Cldf = (float*)smemraw;
  const int t = threadIdx.x, wave = t >> 6, lane = t & 63;
  const int m16 = lane & 15, q4 = lane >> 4;
  const int wm = wave >> 1, wn = wave & 1;          // 2x2 waves, each 64x64
  const int bid = blockIdx.x;
  const int nb = bid & 7;                           // nb == XCD: Wo panel L2-local
  const int mb = bid >> 3;                          // 0..31
  // staging: 32 units of 8 rows x 64k (1 KB); wave w owns units w*8..w*8+7
  const int lrow = lane >> 3;
  const int lsegsw = ((lane & 7) ^ lrow) * 8;       // pre-swizzled global seg
  const unsigned short* gsrc[8];
#pragma unroll
  for (int j = 0; j < 8; j++) {
    int u = wave * 8 + j;
    gsrc[j] = (u < 16 ? A  + (size_t)(mb * 128 + u * 8 + lrow) * KDIM
                      : Bm + (size_t)(nb * 128 + (u - 16) * 8 + lrow) * KDIM)
              + lsegsw;
  }
  const int rsw = (m16 & 7) * 8;                    // read-side swizzle (u16 XOR)

  f32x4 acc[4][4];
#pragma unroll
  for (int i_ = 0; i_ < 4; i_++)
#pragma unroll
    for (int j_ = 0; j_ < 4; j_++) acc[i_][j_] = (f32x4){0.f, 0.f, 0.f, 0.f};

  // prologue: issue tile 0 -> slab 0
#pragma unroll
  for (int j = 0; j < 8; j++)
    gload_lds16(gsrc[j], smem + (wave * 8 + j) * 512);
  __builtin_amdgcn_sched_barrier(0);

  for (int T = 0; T < 16; ++T) {
    const int c = T & 1;
    const unsigned short* As = smem + c * 16384;
    const unsigned short* Bs = As + 8192;
    unsigned short* nslab = smem + (c ^ 1) * 16384;
    const int nkt = (T + 1) * 64;
    const bool st = (T < 15);

    if (st) {
#pragma unroll
      for (int j = 0; j < 8; j++)
        gload_lds16(gsrc[j] + nkt, nslab + (wave * 8 + j) * 512);
    }
    __builtin_amdgcn_sched_barrier(0);
    if (st) asm volatile("s_waitcnt vmcnt(8)" ::: "memory");  // tile T landed, T+1 in flight
    else    asm volatile("s_waitcnt vmcnt(0)" ::: "memory");
    __builtin_amdgcn_sched_barrier(0);
    __builtin_amdgcn_s_barrier();
    __builtin_amdgcn_sched_barrier(0);
#pragma unroll
    for (int h = 0; h < 2; h++) {
      short8 af[4], bf[4];
#pragma unroll
      for (int mt = 0; mt < 4; mt++)
        af[mt] = *reinterpret_cast<const short8*>(
            &As[(wm * 64 + mt * 16 + m16) * 64 + (((h * 4 + q4) * 8) ^ rsw)]);
#pragma unroll
      for (int nt = 0; nt < 4; nt++)
        bf[nt] = *reinterpret_cast<const short8*>(
            &Bs[(wn * 64 + nt * 16 + m16) * 64 + (((h * 4 + q4) * 8) ^ rsw)]);
      asm volatile("s_waitcnt lgkmcnt(0)" ::: "memory");
      __builtin_amdgcn_sched_barrier(0);
      __builtin_amdgcn_s_setprio(1);
#pragma unroll
      for (int mt = 0; mt < 4; mt++)
#pragma unroll
        for (int nt = 0; nt < 4; nt++)
          acc[mt][nt] = __builtin_amdgcn_mfma_f32_16x16x32_bf16(af[mt], bf[nt], acc[mt][nt], 0, 0, 0);
      __builtin_amdgcn_s_setprio(0);
      __builtin_amdgcn_sched_barrier(0);
    }
    __builtin_amdgcn_sched_barrier(0);
    __builtin_amdgcn_s_barrier();
    __builtin_amdgcn_sched_barrier(0);
  }

  // ---- epilogue: bias add via LDS f32 [128][132], coalesced f32 writeout ----
#pragma unroll
  for (int nt = 0; nt < 4; nt++) {
    int cloc = wn * 64 + nt * 16 + m16;
    float bv = bias[nb * 128 + cloc];
#pragma unroll
    for (int mt = 0; mt < 4; mt++) {
#pragma unroll
      for (int reg = 0; reg < 4; reg++) {
        int rloc = wm * 64 + mt * 16 + q4 * 4 + reg;
        Cldf[rloc * 132 + cloc] = acc[mt][nt][reg] + bv;
      }
    }
  }
  __syncthreads();
  {
    int r = t >> 1, half = t & 1;   // 128 rows x 2 halves of 64 floats (256 B)
    float* dst = out + (size_t)(mb * 128 + r) * EMBED + nb * 128 + half * 64;
    const float* srcl = &Cldf[r * 132 + half * 64];
#pragma unroll
    for (int j = 0; j < 16; j++)
      *reinterpret_cast<float4*>(dst + j * 4) = *reinterpret_cast<const float4*>(srcl + j * 4);
  }
}

// ---------------- banded attention v5: staged K/V, split-wait (T4) ----------------
// v3 + counted vmcnt: issue q(2), K units(10), V units(10); wait vmcnt(10) -> q+K landed,
// V's 40 KB stays in flight under the QK^T+softmax phase; the mid-kernel __syncthreads
// (implicit vmcnt(0)) lands V block-wide exactly where PV needs it.
__global__ __launch_bounds__(256, 2) void attn_kernel(
    const unsigned short* __restrict__ q, const unsigned short* __restrict__ k,
    const unsigned short* __restrict__ vTp, unsigned short* __restrict__ vals)
{
  __shared__ __align__(16) unsigned short smem[40960];   // 81,920 B
  unsigned short* Ks = smem;            // [320][64] u16 (40,960 B)
  unsigned short* Vs = smem + 20480;    // [64][320] u16 (40,960 B)
  unsigned short* Pld = smem;           // alias over Ks after QK phase: [4][16][296]

  const int bid = blockIdx.x;
  const int bh = bid & 31, qg = bid >> 5;                // bh-fastest: XCD-local K/V
  const int lane = threadIdx.x & 63, wave = threadIdx.x >> 6;
  const int i0b = qg * 64;
  const int i0 = i0b + wave * 16;
  const int m16 = lane & 15, q4 = lane >> 4;

  // ---- q fragments FIRST (oldest in vmcnt queue; retired by the vmcnt(10) wait) ----
  const unsigned short* qb = q + ((size_t)(bh * 2048 + i0 + m16)) * 64 + q4 * 8;
  short8 aq0 = *reinterpret_cast<const short8*>(qb);
  short8 aq1 = *reinterpret_cast<const short8*>(qb + 32);
  __builtin_amdgcn_sched_barrier(0);

  // ---- stage K window: 40 KB = 10 wave-issues of 1 KB per wave ----
  const unsigned short* kbase = k + (size_t)bh * 2048 * 64;
#pragma unroll
  for (int n = 0; n < 10; n++) {
    int idx = (n * 4 + wave) * 64 + lane;      // 0..2559
    int krow = idx >> 3, seg = idx & 7;
    int grow = i0b - 128 + krow;
    grow = grow < 0 ? 0 : (grow > 2047 ? 2047 : grow);
    int lseg = seg ^ (krow & 7);               // store swizzled within 128B row
    gload_lds16(kbase + (size_t)grow * 64 + lseg * 8, Ks + (n * 4 + wave) * 512);
  }
  __builtin_amdgcn_sched_barrier(0);
  // ---- stage V^T window: 40 KB, rows of 320 u16 (40 segs of 16B) ----
  const unsigned short* vbase = vTp + (size_t)bh * 64 * SP + i0b;  // col(i0b) == key i0b-128
#pragma unroll
  for (int n = 0; n < 10; n++) {
    int idx = (n * 4 + wave) * 64 + lane;      // 0..2559
    int vrow = idx / 40, rem = idx % 40;
    int l = (rem & ~7) | ((rem & 7) ^ (vrow & 7));
    gload_lds16(vbase + (size_t)vrow * SP + l * 8, Vs + (n * 4 + wave) * 512);
  }
  __builtin_amdgcn_sched_barrier(0);

  // counted wait: q(2)+K(10) retired, V(10) in flight; raw barrier (no drain)
  asm volatile("s_waitcnt vmcnt(10)" ::: "memory");
  __builtin_amdgcn_sched_barrier(0);
  __builtin_amdgcn_s_barrier();
  __builtin_amdgcn_sched_barrier(0);

  // ---- QK^T + streaming exp, P packed in registers (V still landing underneath) ----
  float sum[4] = {0.f, 0.f, 0.f, 0.f};
  uint32_t pP[18][2];
#pragma unroll
  for (int ct = 0; ct < 18; ct++) {
    int r = (wave + ct) * 16 + m16;            // LDS key row (may run past 320: finite data, masked)
    int js = i0b - 128 + r;                    // global key index
    const unsigned short* kr = Ks + r * 64;
    short8 b0 = *reinterpret_cast<const short8*>(kr + ((q4 ^ (r & 7)) * 8));
    short8 b1 = *reinterpret_cast<const short8*>(kr + (((q4 + 4) ^ (r & 7)) * 8));
    f32x4 a = {0.f, 0.f, 0.f, 0.f};
    a = __builtin_amdgcn_mfma_f32_16x16x32_bf16(aq0, b0, a, 0, 0, 0);
    a = __builtin_amdgcn_mfma_f32_16x16x32_bf16(aq1, b1, a, 0, 0, 0);
    unsigned short pe[4];
#pragma unroll
    for (int reg = 0; reg < 4; reg++) {
      int i = i0 + q4 * 4 + reg;
      bool valid = (js >= 0) && (js < 2048) && (js >= i - 128) && (js <= i + 128);
      float e = valid ? __expf(a[reg] * 0.125f) : 0.0f;
      sum[reg] += e;
      pe[reg] = f2bf(e);
    }
    pP[ct][0] = (uint32_t)pe[0] | ((uint32_t)pe[1] << 16);
    pP[ct][1] = (uint32_t)pe[2] | ((uint32_t)pe[3] << 16);
  }
  float rden[4];
#pragma unroll
  for (int reg = 0; reg < 4; reg++) {
    float s = sum[reg];
    s += __shfl_xor(s, 1);
    s += __shfl_xor(s, 2);
    s += __shfl_xor(s, 4);
    s += __shfl_xor(s, 8);
    rden[reg] = 1.0f / s;
  }

  __syncthreads();   // implicit vmcnt(0): V landed block-wide; Ks reads done -> Pld may overwrite

  unsigned short* Pw = Pld + wave * 16 * 296;
#pragma unroll
  for (int ct = 0; ct < 18; ct++) {
    Pw[(q4 * 4 + 0) * 296 + ct * 16 + m16] = (unsigned short)(pP[ct][0] & 0xFFFF);
    Pw[(q4 * 4 + 1) * 296 + ct * 16 + m16] = (unsigned short)(pP[ct][0] >> 16);
    Pw[(q4 * 4 + 2) * 296 + ct * 16 + m16] = (unsigned short)(pP[ct][1] & 0xFFFF);
    Pw[(q4 * 4 + 3) * 296 + ct * 16 + m16] = (unsigned short)(pP[ct][1] >> 16);
  }
  // own-wave LDS ordering handled by lgkmcnt; no block barrier needed
  short8 ap[9];
#pragma unroll
  for (int kc = 0; kc < 9; kc++)
    ap[kc] = *reinterpret_cast<const short8*>(&Pw[m16 * 296 + kc * 32 + q4 * 8]);

  const int b = bh >> 4, h = bh & 15;
#pragma unroll
  for (int dt = 0; dt < 4; dt++) {
    int vrow = dt * 16 + m16;
    const unsigned short* vr = Vs + vrow * 320;
    f32x4 av = {0.f, 0.f, 0.f, 0.f};
#pragma unroll
    for (int kc = 0; kc < 9; kc++) {
      int jseg = kc * 4 + wave * 2 + q4;       // logical 16B seg within V^T row
      if (jseg > 39) jseg = 39;                // clamp: clamped segs have P==0
      int sseg = (jseg & ~7) | ((jseg & 7) ^ (vrow & 7));
      short8 bv = *reinterpret_cast<const short8*>(vr + sseg * 8);
      av = __builtin_amdgcn_mfma_f32_16x16x32_bf16(ap[kc], bv, av, 0, 0, 0);
    }
#pragma unroll
    for (int reg = 0; reg < 4; reg++)
      Pw[(q4 * 4 + reg) * 296 + dt * 16 + m16] = f2bf(av[reg] * rden[reg]);
  }
  // coalesced O writeout: 4 lanes x 32B per row -> full 128B lines
  {
    int srow = lane >> 2, seg = lane & 3;
    unsigned short* dst = vals + ((size_t)(b * 2048 + i0 + srow)) * 1024 + h * 64 + seg * 16;
    const unsigned short* srcl = &Pw[srow * 296 + seg * 16];
    *reinterpret_cast<short8*>(dst)     = *reinterpret_cast<const short8*>(srcl);
    *reinterpret_cast<short8*>(dst + 8) = *reinterpret_cast<const short8*>(srcl + 8);
  }
}

extern "C" void kernel_launch(void* const* d_in, const int* in_sizes, int n_in,
                              void* d_out, int out_size, void* d_ws, size_t ws_size,
                              hipStream_t stream) {
  const float* x    = (const float*)d_in[0];
  const int*   pm   = (const int*)d_in[1];
  const float* Wqkv = (const float*)d_in[2];
  const float* bqkv = (const float*)d_in[3];
  const float* Wo   = (const float*)d_in[4];
  const float* bo   = (const float*)d_in[5];
  float* out = (float*)d_out;
  char* ws = (char*)d_ws;

  unsigned short* xb    = (unsigned short*)(ws);                 //  8,388,608
  unsigned short* vals  = (unsigned short*)(ws);                 //  reuse (xb dead after gemm_qkv)
  unsigned short* Wqkvb = (unsigned short*)(ws +  8388608);      //  6,291,456
  unsigned short* Wob   = (unsigned short*)(ws + 14680064);      //  2,097,152
  unsigned short* qbuf  = (unsigned short*)(ws + 16777216);      //  8,388,608
  unsigned short* kbuf  = (unsigned short*)(ws + 25165824);      //  8,388,608
  unsigned short* vTp   = (unsigned short*)(ws + 33554432);      //  9,568,256 (ends 43,122,688)

  cvt3_kernel<<<8768, 256, 0, stream>>>(x, Wqkv, Wo, xb, Wqkvb, Wob, vTp);
  gemm_qkv<<<256, 512, 0, stream>>>(xb, Wqkvb, bqkv, pm, qbuf, kbuf, vTp);
  attn_kernel<<<1024, 256, 0, stream>>>(qbuf, kbuf, vTp, vals);
  gemm_out<<<256, 256, 0, stream>>>(vals, Wob, bo, out);
}